// Round 11
// baseline (182.065 us; speedup 1.0000x reference)
//
#include <hip/hip_runtime.h>
#include <math.h>

#define NWG 256
#define NPAIR 128
#define NITER 3
#define NBATCH 8192
#define KDIM 512
#define MSZ (512*512)   // elems per embedded matrix

typedef __attribute__((ext_vector_type(8))) short short8;
typedef __attribute__((ext_vector_type(8))) unsigned short ushort8v;
typedef __attribute__((ext_vector_type(4))) float floatx4;

static __device__ __forceinline__ unsigned short f2bf(float f) {
    unsigned int u = __float_as_uint(f);
    unsigned int r = (u + 0x7fffu + ((u >> 16) & 1u)) >> 16;
    return (unsigned short)r;
}
static __device__ __forceinline__ float bf2f(unsigned short h) {
    return __uint_as_float(((unsigned int)h) << 16);
}
static __device__ __forceinline__ void bsplit(float v, unsigned short &h, unsigned short &l) {
    h = f2bf(v);
    l = f2bf(v - bf2f(h));
}
static __device__ __forceinline__ void async16(const void* g, void* l) {
    __builtin_amdgcn_global_load_lds(
        (const __attribute__((address_space(1))) unsigned int*)g,
        (__attribute__((address_space(3))) unsigned int*)l, 16, 0, 0);
}

static __device__ __forceinline__ void apply2(
    float &x0r, float &x0i, float &x1r, float &x1i,
    const float4 a, const float4 b)
{
    float y0r = a.x*x0r - a.y*x0i + a.z*x1r - a.w*x1i;
    float y0i = a.x*x0i + a.y*x0r + a.z*x1i + a.w*x1r;
    float y1r = b.x*x0r - b.y*x0i + b.z*x1r - b.w*x1i;
    float y1i = b.x*x0i + b.y*x0r + b.z*x1i + b.w*x1r;
    x0r = y0r; x0i = y0i; x1r = y1r; x1i = y1i;
}

// coef: rows (A,B),(C,D); coefT: transposed rows (A,C),(B,D); gexp: {cos,sin}
__global__ void precompute_kernel(const float* __restrict__ theta,
                                  const float* __restrict__ phi,
                                  const float* __restrict__ gamma,
                                  float* __restrict__ coef,
                                  float* __restrict__ coefT,
                                  float* __restrict__ gexp)
{
    int idx = blockIdx.x * blockDim.x + threadIdx.x;
    if (idx < NITER * NWG * NPAIR) {
        float h  = 0.5f * theta[idx];
        float ph = phi[idx];
        float sh = sinf(h),  ch = cosf(h);
        float sp = sinf(ph), cp = cosf(ph);
        float pr = -sh, pii = ch;            // pre = i*exp(i*h)
        float qr = pr*cp - pii*sp;           // pre*exp(i*ph)
        float qi = pr*sp + pii*cp;
        float Ar = qr*sh,  Ai = qi*sh;
        float Br = pr*ch,  Bi = pii*ch;
        float Cr = qr*ch,  Ci = qi*ch;
        float Dr = -pr*sh, Di = -pii*sh;
        float4* o = (float4*)coef + (size_t)idx * 2;
        o[0] = make_float4(Ar,Ai,Br,Bi);
        o[1] = make_float4(Cr,Ci,Dr,Di);
        float4* ot = (float4*)coefT + (size_t)idx * 2;
        ot[0] = make_float4(Ar,Ai,Cr,Ci);
        ot[1] = make_float4(Br,Bi,Dr,Di);
    }
    if (idx < NITER * NWG) {
        float g = gamma[idx];
        gexp[idx*2]   = cosf(g);
        gexp[idx*2+1] = sinf(g);
    }
}

// Store one propagated row as the 2x2 real embedding (hi/lo bf16 split).
static __device__ __forceinline__ void store_row(
    unsigned short* __restrict__ bh, unsigned short* __restrict__ bl,
    int row, int lane, bool cj, const float xr[4], const float xi[4])
{
    ushort4 reH, reL, imH, imL, nimH, nimL;
    unsigned short h, l;
#pragma unroll
    for (int e = 0; e < 4; ++e) {
        bsplit(xr[e], h, l);  ((unsigned short*)&reH)[e]  = h; ((unsigned short*)&reL)[e]  = l;
        bsplit(xi[e], h, l);  ((unsigned short*)&imH)[e]  = h; ((unsigned short*)&imL)[e]  = l;
        bsplit(-xi[e], h, l); ((unsigned short*)&nimH)[e] = h; ((unsigned short*)&nimL)[e] = l;
    }
    // plain:  [[Re, -Im],[ Im, Re]] ; conj: [[Re, +Im],[-Im, Re]]
    ushort4 urH = cj ? imH : nimH, urL = cj ? imL : nimL;   // upper-right
    ushort4 llH = cj ? nimH : imH, llL = cj ? nimL : imL;   // lower-left
    *(ushort4*)(bh + (size_t)row*KDIM + 4*lane)             = reH;
    *(ushort4*)(bh + (size_t)row*KDIM + 256 + 4*lane)       = urH;
    *(ushort4*)(bh + (size_t)(row+256)*KDIM + 4*lane)       = llH;
    *(ushort4*)(bh + (size_t)(row+256)*KDIM + 256 + 4*lane) = reH;
    *(ushort4*)(bl + (size_t)row*KDIM + 4*lane)             = reL;
    *(ushort4*)(bl + (size_t)row*KDIM + 256 + 4*lane)       = urL;
    *(ushort4*)(bl + (size_t)(row+256)*KDIM + 4*lane)       = llL;
    *(ushort4*)(bl + (size_t)(row+256)*KDIM + 256 + 4*lane) = reL;
}

// One MZI layer applied to TWO row states (a*, b*) sharing one coefficient set.
// cc[0..3] = (c0a,c0b,c1a,c1b). sp = physical layer index (parity selects path).
static __device__ __forceinline__ void layer_compute2(
    const float4 cc[4], int lane, int sp,
    float ar[4], float ai[4], float br[4], float bi[4])
{
    const float4 c0a = cc[0], c0b = cc[1], c1a = cc[2], c1b = cc[3];
    if ((sp & 1) == 0) {
        apply2(ar[0], ai[0], ar[1], ai[1], c0a, c0b);
        apply2(ar[2], ai[2], ar[3], ai[3], c1a, c1b);
        apply2(br[0], bi[0], br[1], bi[1], c0a, c0b);
        apply2(br[2], bi[2], br[3], bi[3], c1a, c1b);
    } else {
        float tAr = __shfl_down(ar[0], 1, 64);
        float tAi = __shfl_down(ai[0], 1, 64);
        float tBr = __shfl_down(br[0], 1, 64);
        float tBi = __shfl_down(bi[0], 1, 64);
        apply2(ar[1], ai[1], ar[2], ai[2], c0a, c0b);
        apply2(br[1], bi[1], br[2], bi[2], c0a, c0b);
        // row A boundary pair (4l+3, next lane's 4l+0)
        float x3r = ar[3], x3i = ai[3];
        float y3r = c1a.x*x3r - c1a.y*x3i + c1a.z*tAr - c1a.w*tAi;
        float y3i = c1a.x*x3i + c1a.y*x3r + c1a.z*tAi + c1a.w*tAr;
        float ynr = c1b.x*x3r - c1b.y*x3i + c1b.z*tAr - c1b.w*tAi;
        float yni = c1b.x*x3i + c1b.y*x3r + c1b.z*tAi + c1b.w*tAr;
        // row B boundary pair
        float w3r = br[3], w3i = bi[3];
        float z3r = c1a.x*w3r - c1a.y*w3i + c1a.z*tBr - c1a.w*tBi;
        float z3i = c1a.x*w3i + c1a.y*w3r + c1a.z*tBi + c1a.w*tBr;
        float znr = c1b.x*w3r - c1b.y*w3i + c1b.z*tBr - c1b.w*tBi;
        float zni = c1b.x*w3i + c1b.y*w3r + c1b.z*tBi + c1b.w*tBr;
        float rAr = __shfl_up(ynr, 1, 64);
        float rAi = __shfl_up(yni, 1, 64);
        float rBr = __shfl_up(znr, 1, 64);
        float rBi = __shfl_up(zni, 1, 64);
        if (lane != 63) { ar[3] = y3r; ai[3] = y3i; br[3] = z3r; bi[3] = z3i; }
        if (lane != 0)  { ar[0] = rAr; ai[0] = rAi; br[0] = rBr; bi[0] = rBi; }
    }
}

// 24 groups (it, chunk c=0..7), 32 layers each: halves the serial chain depth
// vs the 4x64 split (propagate is stall-bound on its dependent chain; rounds
// 2/4/7 falsified all throughput theories). chunk even: forward (S=Q^T);
// odd: reverse-transposed (S=Q); chunk 7 starts with gamma (S7=G*Q7).
// Chunks with (c&3) in {1,2} stored CONJUGATE-embedded (B-operands of the
// round-1 compose). 128 threads/block, 2 waves x 2 rows; LDS-staged coefs,
// 4 layers/stage, 3-buffer rotation, counted vmcnt, 1 barrier per 4 layers.
__global__ void propagate_kernel(const float* __restrict__ coef,
                                 const float* __restrict__ coefT,
                                 const float* __restrict__ gexp,
                                 unsigned short* __restrict__ chunkH,
                                 unsigned short* __restrict__ chunkL)
{
    __shared__ __align__(16) char smem[3 * 16384];   // 3 stages x 4 rows x 4KB

    const int tid  = threadIdx.x;              // 0..127
    const int lane = tid & 63;
    const int wv   = tid >> 6;                 // 0..1
    const int grp  = blockIdx.x >> 6;          // 0..23
    const int it   = grp >> 3, c = grp & 7;
    const int r0   = (blockIdx.x & 63) * 4 + wv * 2;   // this wave's rows
    const int r1   = r0 + 1;
    const bool rev = (c & 1);
    const bool cj  = ((c & 3) == 1) || ((c & 3) == 2);   // conj-embedded storage

    float ar[4], ai[4], br[4], bi[4];
    float gc0 = 1.0f, gs0 = 0.0f, gc1 = 1.0f, gs1 = 0.0f;
    if (c == 7) {
        gc0 = gexp[(it*NWG + r0)*2]; gs0 = gexp[(it*NWG + r0)*2 + 1];
        gc1 = gexp[(it*NWG + r1)*2]; gs1 = gexp[(it*NWG + r1)*2 + 1];
    }
#pragma unroll
    for (int e = 0; e < 4; ++e) {
        bool on0 = (4*lane + e) == r0;
        bool on1 = (4*lane + e) == r1;
        ar[e] = on0 ? gc0 : 0.0f;  ai[e] = on0 ? gs0 : 0.0f;
        br[e] = on1 ? gc1 : 0.0f;  bi[e] = on1 ? gs1 : 0.0f;
    }

    const char* cbb = (const char*)(rev ? coefT : coef)
                    + (size_t)(it*NWG + c*32) * (NPAIR * 32);   // 4096 B per layer row
    const int slot16 = (tid ^ ((tid >> 3) & 3)) * 16;

    auto stage = [&](int m) {
        char* dst = smem + (m % 3) * 16384;
#pragma unroll
        for (int q = 0; q < 4; ++q) {
            int s = 4*m + q;
            int r = rev ? 31 - s : s;
            const char* srow = cbb + (size_t)r * 4096;
            async16(srow + slot16,        dst + q*4096 + tid*16);
            async16(srow + slot16 + 2048, dst + q*4096 + tid*16 + 2048);
        }
    };

    stage(0); stage(1);                        // 16 loads in flight per thread

    const int sw = (lane >> 1) & 3;
    for (int m = 0; m < 8; ++m) {
        if (m < 7) asm volatile("s_waitcnt vmcnt(8)" ::: "memory");
        else       asm volatile("s_waitcnt vmcnt(0)" ::: "memory");
        __builtin_amdgcn_s_barrier();
        asm volatile("" ::: "memory");
        if (m < 6) stage(m + 2);
        const char* B = smem + (m % 3) * 16384;

        float4 cc[4][4];
#pragma unroll
        for (int q = 0; q < 4; ++q) {
            const char* Bq = B + q*4096;
            cc[q][0] = *(const float4*)(Bq + 16*(4*lane + (0 ^ sw)));
            cc[q][1] = *(const float4*)(Bq + 16*(4*lane + (1 ^ sw)));
            cc[q][2] = *(const float4*)(Bq + 16*(4*lane + (2 ^ sw)));
            cc[q][3] = *(const float4*)(Bq + 16*(4*lane + (3 ^ sw)));
        }
#pragma unroll
        for (int q = 0; q < 4; ++q) {
            int s = 4*m + q;
            layer_compute2(cc[q], lane, rev ? 31 - s : s, ar, ai, br, bi);
        }
    }

    unsigned short* bh = chunkH + (size_t)grp * MSZ;
    unsigned short* bl = chunkL + (size_t)grp * MSZ;
    store_row(bh, bl, r0, lane, cj, ar, ai);
    store_row(bh, bl, r1, lane, cj, br, bi);
}

// C = Ah*Bh^T + Ah*Bl^T + Al*Bh^T  (512x512, 64x64 tiles), 3-round tree:
// round 1 (z=it*4+w): pairs chunks a={0,3,4,7}[w], b={1,2,5,6}[w] ->
//   {D0^T, D1, D2^T, D3}; conj-store w in {1,2} (B-operands of round 2).
// round 2 (z=it*2+w): a=idx{0,3}, b=idx{1,2} -> {E0^T (conj), E1 (plain)}.
// round 3 (z=it): E(M) = E1 * (E0^T)^T -> bmat (single bf16).
// All rounds: B-operand conj-embedded so real A*B^T = E(Sa*Sb^T).
// K-loop: 3-stage LDS pipeline, counted vmcnt(4), ONE barrier per K-step.
__global__ __launch_bounds__(256, 2) void compose_kernel(
    const unsigned short* __restrict__ srcH, const unsigned short* __restrict__ srcL,
    unsigned short* __restrict__ outH, unsigned short* __restrict__ outL,
    unsigned short* __restrict__ bmat, int round)
{
    __shared__ unsigned short sAh[3][2048], sAl[3][2048], sBh[3][2048], sBl[3][2048];
    const int z = blockIdx.z;
    const unsigned short *Ah, *Al, *Bh, *Bl;
    bool conjOut = false;
    if (round == 1) {
        const int aoff[4] = {0, 3, 4, 7}, boff[4] = {1, 2, 5, 6};
        int w = z & 3, it = z >> 2;
        int ac = it*8 + aoff[w], bc = it*8 + boff[w];
        conjOut = (w == 1) || (w == 2);
        Ah = srcH + (size_t)ac*MSZ; Al = srcL + (size_t)ac*MSZ;
        Bh = srcH + (size_t)bc*MSZ; Bl = srcL + (size_t)bc*MSZ;
    } else if (round == 2) {
        int w = z & 1, it = z >> 1;
        int ac = it*4 + (w ? 3 : 0), bc = it*4 + (w ? 2 : 1);
        conjOut = (w == 0);
        Ah = srcH + (size_t)ac*MSZ; Al = srcL + (size_t)ac*MSZ;
        Bh = srcH + (size_t)bc*MSZ; Bl = srcL + (size_t)bc*MSZ;
    } else {
        Ah = srcH + (size_t)(2*z+1)*MSZ; Al = srcL + (size_t)(2*z+1)*MSZ;
        Bh = srcH + (size_t)(2*z)*MSZ;   Bl = srcL + (size_t)(2*z)*MSZ;
    }
    const int tid = threadIdx.x, lane = tid & 63, wv = tid >> 6;
    const int quad = lane >> 4, l16 = lane & 15;
    const int m0 = blockIdx.x * 64, n0 = blockIdx.y * 64;
    const unsigned short* src = (wv==0)?Ah:(wv==1)?Al:(wv==2)?Bh:Bl;
    unsigned short (*dstb)[2048] = (wv==0)?sAh:(wv==1)?sAl:(wv==2)?sBh:sBl;
    const int r0 = (wv < 2) ? m0 : n0;
    const int trowb = lane >> 2, tcol = (lane & 3) * 8;

    const unsigned short* sp[4];
#pragma unroll
    for (int i = 0; i < 4; ++i)
        sp[i] = src + (size_t)(r0 + i*16 + trowb)*KDIM + tcol;

    auto stage = [&](int s) {
        int kt = s * 32, bs = s % 3;
#pragma unroll
        for (int i = 0; i < 4; ++i)
            async16(sp[i] + kt, &dstb[bs][i*512 + lane*8]);
    };
    stage(0); stage(1);                        // 8 loads in flight per thread

    floatx4 acc[4] = {};
    for (int s = 0; s < 16; ++s) {
        if (s < 15) asm volatile("s_waitcnt vmcnt(4)" ::: "memory");
        else        asm volatile("s_waitcnt vmcnt(0)" ::: "memory");
        __builtin_amdgcn_s_barrier();
        asm volatile("" ::: "memory");
        if (s < 14) stage(s + 2);
        const int bs = s % 3;
        short8 ah = *(const short8*)&sAh[bs][(16*wv + l16)*32 + quad*8];
        short8 al = *(const short8*)&sAl[bs][(16*wv + l16)*32 + quad*8];
#pragma unroll
        for (int ni = 0; ni < 4; ++ni) {
            short8 bh = *(const short8*)&sBh[bs][(16*ni + l16)*32 + quad*8];
            short8 bl = *(const short8*)&sBl[bs][(16*ni + l16)*32 + quad*8];
            acc[ni] = __builtin_amdgcn_mfma_f32_16x16x32_bf16(ah, bh, acc[ni], 0,0,0);
            acc[ni] = __builtin_amdgcn_mfma_f32_16x16x32_bf16(ah, bl, acc[ni], 0,0,0);
            acc[ni] = __builtin_amdgcn_mfma_f32_16x16x32_bf16(al, bh, acc[ni], 0,0,0);
        }
    }
#pragma unroll
    for (int ni = 0; ni < 4; ++ni)
#pragma unroll
        for (int rg = 0; rg < 4; ++rg) {
            int r = m0 + 16*wv + quad*4 + rg;
            int cc = n0 + 16*ni + l16;
            float v = acc[ni][rg];
            if (round <= 2) {
                float vs = (conjOut && ((r >= 256) != (cc >= 256))) ? -v : v;
                unsigned short h, l; bsplit(vs, h, l);
                outH[(size_t)z*MSZ + (size_t)r*KDIM + cc] = h;
                outL[(size_t)z*MSZ + (size_t)r*KDIM + cc] = l;
            } else {
                bmat[(size_t)z*MSZ + (size_t)r*KDIM + cc] = f2bf(v);
            }
        }
}

// Fused tail: convert + gemm0(EO) + gemm1(EO) + gemm2(intensity) + row-norm.
// 256 blocks x 512 threads (8 waves); block b owns rows [32b, 32b+32).
// (Verified round 10: -48 MB HBM, -3 dispatches vs separate kernels.)
__global__ __launch_bounds__(512, 1) void fused_tail_kernel(
    const unsigned short* __restrict__ Bmat,
    const float* __restrict__ xre, const float* __restrict__ xim,
    float* __restrict__ out)
{
    __shared__ __align__(16) char lds[131072];   // 96KB B (3 stages) + 32KB sX
    const int tid = threadIdx.x, lane = tid & 63, wv = tid >> 6;
    const int quad = lane >> 4, l16 = lane & 15;
    const int rbase = blockIdx.x * 32;
    const int nb = 32 * wv;

    // sX: row-major [32][512] bf16 at lds+98304, byte ^= ((row&7)<<4) swizzle
    auto sx = [&](int row, int colByte) -> char* {
        return lds + 98304 + row*1024 + (colByte ^ ((row & 7) << 4));
    };

    // ---- stage x (fp32 -> bf16) into sX
    {
        float4 v0[4], v1[4]; int xr_[4], xc_[4];
#pragma unroll
        for (int c = 0; c < 4; ++c) {
            int k = tid + c*512;
            int row = k >> 6, rem = k & 63, half = rem >> 5, j8 = (rem & 31) << 3;
            const float* s = (half ? xim : xre) + ((size_t)(rbase + row))*256 + j8;
            v0[c] = *(const float4*)s; v1[c] = *(const float4*)(s + 4);
            xr_[c] = row; xc_[c] = (half*256 + j8)*2;
        }
        asm volatile("s_waitcnt vmcnt(0)" ::: "memory");
#pragma unroll
        for (int c = 0; c < 4; ++c) {
            ushort8v u;
            u[0]=f2bf(v0[c].x); u[1]=f2bf(v0[c].y); u[2]=f2bf(v0[c].z); u[3]=f2bf(v0[c].w);
            u[4]=f2bf(v1[c].x); u[5]=f2bf(v1[c].y); u[6]=f2bf(v1[c].z); u[7]=f2bf(v1[c].w);
            *(ushort8v*)sx(xr_[c], xc_[c]) = u;
        }
    }

    auto stageB = [&](int t) {
        const unsigned short* src = Bmat + ((size_t)(t >> 4))*MSZ + (size_t)(t & 15)*32;
        char* dst = lds + (t % 3)*32768;
#pragma unroll
        for (int c = 0; c < 4; ++c) {
            int slot = tid + c*512, r = slot >> 2, q = slot & 3;
            async16(src + (size_t)r*KDIM + q*8, dst + slot*16);
        }
    };
    stageB(0); stageB(1);                      // 8 loads in flight per thread
    asm volatile("s_waitcnt lgkmcnt(0)" ::: "memory");

    floatx4 accr[2][2] = {}, acci[2][2] = {};

    for (int t = 0; t < 48; ++t) {
        if (t < 46) asm volatile("s_waitcnt vmcnt(4)" ::: "memory");
        else        asm volatile("s_waitcnt vmcnt(0)" ::: "memory");
        __builtin_amdgcn_s_barrier();          // stage t visible; readers of t-1 done
        asm volatile("" ::: "memory");
        if (t < 46) stageB(t + 2);             // buf (t+2)%3 last read at t-1

        if (t == 16 || t == 32) {
            // EO boundary: all reads of sX done (barrier above); rewrite in place
#pragma unroll
            for (int f = 0; f < 2; ++f)
#pragma unroll
            for (int nl = 0; nl < 2; ++nl)
#pragma unroll
            for (int rg = 0; rg < 4; ++rg) {
                float yr = accr[f][nl][rg], yi = acci[f][nl][rg];
                float I = yr*yr + yi*yi;
                float ph = 0.078539816339744831f * I + 1.5707963267948966f;
                float sp, cp; __sincosf(ph, &sp, &cp);
                float fm = 0.94868329805051381f * cp;
                int row = 16*f + quad*4 + rg;
                int col = nb + 16*nl + l16;
                *(unsigned short*)sx(row, col*2)       = f2bf(fm*(cp*yr + sp*yi));
                *(unsigned short*)sx(row, col*2 + 512) = f2bf(fm*(cp*yi - sp*yr));
            }
            asm volatile("s_waitcnt lgkmcnt(0)" ::: "memory");
            __builtin_amdgcn_s_barrier();
            asm volatile("" ::: "memory");
#pragma unroll
            for (int f = 0; f < 2; ++f)
#pragma unroll
            for (int nl = 0; nl < 2; ++nl) {
                accr[f][nl] = (floatx4){0.f,0.f,0.f,0.f};
                acci[f][nl] = (floatx4){0.f,0.f,0.f,0.f};
            }
        }

        const int kB = (t & 15) * 64;          // col-byte base in sX
        const char* Bb = lds + (t % 3)*32768;
        short8 a0 = *(const short8*)sx(l16,      kB + quad*16);
        short8 a1 = *(const short8*)sx(16 + l16, kB + quad*16);
        short8 br0 = *(const short8*)(Bb + (nb + l16)*64 + quad*16);
        short8 br1 = *(const short8*)(Bb + (nb + 16 + l16)*64 + quad*16);
        short8 bi0 = *(const short8*)(Bb + (256 + nb + l16)*64 + quad*16);
        short8 bi1 = *(const short8*)(Bb + (256 + nb + 16 + l16)*64 + quad*16);
        accr[0][0] = __builtin_amdgcn_mfma_f32_16x16x32_bf16(a0, br0, accr[0][0], 0,0,0);
        accr[0][1] = __builtin_amdgcn_mfma_f32_16x16x32_bf16(a0, br1, accr[0][1], 0,0,0);
        accr[1][0] = __builtin_amdgcn_mfma_f32_16x16x32_bf16(a1, br0, accr[1][0], 0,0,0);
        accr[1][1] = __builtin_amdgcn_mfma_f32_16x16x32_bf16(a1, br1, accr[1][1], 0,0,0);
        acci[0][0] = __builtin_amdgcn_mfma_f32_16x16x32_bf16(a0, bi0, acci[0][0], 0,0,0);
        acci[0][1] = __builtin_amdgcn_mfma_f32_16x16x32_bf16(a0, bi1, acci[0][1], 0,0,0);
        acci[1][0] = __builtin_amdgcn_mfma_f32_16x16x32_bf16(a1, bi0, acci[1][0], 0,0,0);
        acci[1][1] = __builtin_amdgcn_mfma_f32_16x16x32_bf16(a1, bi1, acci[1][1], 0,0,0);
    }

    // ---- epilogue: intensity + cross-wave row norm + 10-col output ----
    float I[2][2][4];
    float p[2][4];
#pragma unroll
    for (int f = 0; f < 2; ++f)
#pragma unroll
    for (int rg = 0; rg < 4; ++rg) {
        float s = 0.0f;
#pragma unroll
        for (int nl = 0; nl < 2; ++nl) {
            float yr = accr[f][nl][rg], yi = acci[f][nl][rg];
            float Iv = yr*yr + yi*yi;
            I[f][nl][rg] = Iv;
            s += Iv*Iv;
        }
        p[f][rg] = s;
    }
#pragma unroll
    for (int d = 1; d < 16; d <<= 1) {
#pragma unroll
        for (int f = 0; f < 2; ++f)
#pragma unroll
        for (int rg = 0; rg < 4; ++rg)
            p[f][rg] += __shfl_xor(p[f][rg], d, 64);   // reduce over l16 (in-quad)
    }
    float* scr = (float*)lds;                  // [8 waves][32 rows]
    if (l16 == 0) {
#pragma unroll
        for (int f = 0; f < 2; ++f)
#pragma unroll
        for (int rg = 0; rg < 4; ++rg)
            scr[wv*32 + 16*f + quad*4 + rg] = p[f][rg];
    }
    asm volatile("s_waitcnt lgkmcnt(0)" ::: "memory");
    __builtin_amdgcn_s_barrier();
    asm volatile("" ::: "memory");
    float* invb = (float*)(lds + 2048);        // [32 rows]
    if (tid < 32) {
        float s = 0.0f;
#pragma unroll
        for (int w = 0; w < 8; ++w) s += scr[w*32 + tid];
        invb[tid] = 1.0f / fmaxf(sqrtf(s), 1e-12f);
    }
    asm volatile("s_waitcnt lgkmcnt(0)" ::: "memory");
    __builtin_amdgcn_s_barrier();
    asm volatile("" ::: "memory");
    if (wv == 0 && l16 < 10) {                 // cols 0..9 live in wave 0, nl=0
#pragma unroll
        for (int f = 0; f < 2; ++f)
#pragma unroll
        for (int rg = 0; rg < 4; ++rg) {
            int row = 16*f + quad*4 + rg;
            out[((size_t)(rbase + row))*10 + l16] = I[f][0][rg] * invb[row];
        }
    }
}

extern "C" void kernel_launch(void* const* d_in, const int* in_sizes, int n_in,
                              void* d_out, int out_size, void* d_ws, size_t ws_size,
                              hipStream_t stream)
{
    const float* x_real = (const float*)d_in[0];
    const float* x_imag = (const float*)d_in[1];
    const float* theta  = (const float*)d_in[2];
    const float* phi    = (const float*)d_in[3];
    const float* gamma  = (const float*)d_in[4];

    char* ws = (char*)d_ws;
    float* coef  = (float*)(ws + 0);                            // 3 MB
    float* coefT = (float*)(ws + 3145728);                      // 3 MB
    float* gexp  = (float*)(ws + 6291456);                      // 6 KB
    unsigned short* chunkH = (unsigned short*)(ws + 6297600);   // 24 x 512KB = 12 MB
    unsigned short* chunkL = (unsigned short*)(ws + 18880512);  // 12 MB
    unsigned short* R1H = (unsigned short*)(ws + 31463424);     // 12 x 512KB = 6 MB
    unsigned short* R1L = (unsigned short*)(ws + 37754880);     // 6 MB
    unsigned short* R2H = (unsigned short*)(ws + 44046336);     // 6 x 512KB = 3 MB
    unsigned short* R2L = (unsigned short*)(ws + 47192064);     // 3 MB
    unsigned short* Bmat = (unsigned short*)(ws + 50337792);    // 1.5 MB

    precompute_kernel<<<(NITER*NWG*NPAIR + 255)/256, 256, 0, stream>>>(
        theta, phi, gamma, coef, coefT, gexp);

    // 1536 blocks x 128 threads: 24 chunks x 64 blocks, 2 waves x 2 rows
    propagate_kernel<<<1536, 128, 0, stream>>>(coef, coefT, gexp, chunkH, chunkL);

    compose_kernel<<<dim3(8,8,12), 256, 0, stream>>>(chunkH, chunkL, R1H, R1L, Bmat, 1);
    compose_kernel<<<dim3(8,8,6),  256, 0, stream>>>(R1H, R1L, R2H, R2L, Bmat, 2);
    compose_kernel<<<dim3(8,8,3),  256, 0, stream>>>(R2H, R2L, (unsigned short*)nullptr,
                                                     (unsigned short*)nullptr, Bmat, 3);

    fused_tail_kernel<<<256, 512, 0, stream>>>(Bmat, x_real, x_imag, (float*)d_out);
}

// Round 12
// 157.302 us; speedup vs baseline: 1.1574x; 1.1574x over previous
//
#include <hip/hip_runtime.h>
#include <math.h>

#define NWG 256
#define NPAIR 128
#define NITER 3
#define NBATCH 8192
#define KDIM 512
#define MSZ (512*512)   // elems per embedded matrix

typedef __attribute__((ext_vector_type(8))) short short8;
typedef __attribute__((ext_vector_type(8))) unsigned short ushort8v;
typedef __attribute__((ext_vector_type(4))) float floatx4;

static __device__ __forceinline__ unsigned short f2bf(float f) {
    unsigned int u = __float_as_uint(f);
    unsigned int r = (u + 0x7fffu + ((u >> 16) & 1u)) >> 16;
    return (unsigned short)r;
}
static __device__ __forceinline__ float bf2f(unsigned short h) {
    return __uint_as_float(((unsigned int)h) << 16);
}
static __device__ __forceinline__ void bsplit(float v, unsigned short &h, unsigned short &l) {
    h = f2bf(v);
    l = f2bf(v - bf2f(h));
}
static __device__ __forceinline__ void async16(const void* g, void* l) {
    __builtin_amdgcn_global_load_lds(
        (const __attribute__((address_space(1))) unsigned int*)g,
        (__attribute__((address_space(3))) unsigned int*)l, 16, 0, 0);
}

static __device__ __forceinline__ void apply2(
    float &x0r, float &x0i, float &x1r, float &x1i,
    const float4 a, const float4 b)
{
    float y0r = a.x*x0r - a.y*x0i + a.z*x1r - a.w*x1i;
    float y0i = a.x*x0i + a.y*x0r + a.z*x1i + a.w*x1r;
    float y1r = b.x*x0r - b.y*x0i + b.z*x1r - b.w*x1i;
    float y1i = b.x*x0i + b.y*x0r + b.z*x1i + b.w*x1r;
    x0r = y0r; x0i = y0i; x1r = y1r; x1i = y1i;
}

// coef: rows (A,B),(C,D); coefT: transposed rows (A,C),(B,D); gexp: {cos,sin}
__global__ void precompute_kernel(const float* __restrict__ theta,
                                  const float* __restrict__ phi,
                                  const float* __restrict__ gamma,
                                  float* __restrict__ coef,
                                  float* __restrict__ coefT,
                                  float* __restrict__ gexp)
{
    int idx = blockIdx.x * blockDim.x + threadIdx.x;
    if (idx < NITER * NWG * NPAIR) {
        float h  = 0.5f * theta[idx];
        float ph = phi[idx];
        float sh = sinf(h),  ch = cosf(h);
        float sp = sinf(ph), cp = cosf(ph);
        float pr = -sh, pii = ch;            // pre = i*exp(i*h)
        float qr = pr*cp - pii*sp;           // pre*exp(i*ph)
        float qi = pr*sp + pii*cp;
        float Ar = qr*sh,  Ai = qi*sh;
        float Br = pr*ch,  Bi = pii*ch;
        float Cr = qr*ch,  Ci = qi*ch;
        float Dr = -pr*sh, Di = -pii*sh;
        float4* o = (float4*)coef + (size_t)idx * 2;
        o[0] = make_float4(Ar,Ai,Br,Bi);
        o[1] = make_float4(Cr,Ci,Dr,Di);
        float4* ot = (float4*)coefT + (size_t)idx * 2;
        ot[0] = make_float4(Ar,Ai,Cr,Ci);
        ot[1] = make_float4(Br,Bi,Dr,Di);
    }
    if (idx < NITER * NWG) {
        float g = gamma[idx];
        gexp[idx*2]   = cosf(g);
        gexp[idx*2+1] = sinf(g);
    }
}

// Store one propagated row as the 2x2 real embedding (hi/lo bf16 split).
static __device__ __forceinline__ void store_row(
    unsigned short* __restrict__ bh, unsigned short* __restrict__ bl,
    int row, int lane, bool cj, const float xr[4], const float xi[4])
{
    ushort4 reH, reL, imH, imL, nimH, nimL;
    unsigned short h, l;
#pragma unroll
    for (int e = 0; e < 4; ++e) {
        bsplit(xr[e], h, l);  ((unsigned short*)&reH)[e]  = h; ((unsigned short*)&reL)[e]  = l;
        bsplit(xi[e], h, l);  ((unsigned short*)&imH)[e]  = h; ((unsigned short*)&imL)[e]  = l;
        bsplit(-xi[e], h, l); ((unsigned short*)&nimH)[e] = h; ((unsigned short*)&nimL)[e] = l;
    }
    // plain:  [[Re, -Im],[ Im, Re]] ; conj: [[Re, +Im],[-Im, Re]]
    ushort4 urH = cj ? imH : nimH, urL = cj ? imL : nimL;   // upper-right
    ushort4 llH = cj ? nimH : imH, llL = cj ? nimL : imL;   // lower-left
    *(ushort4*)(bh + (size_t)row*KDIM + 4*lane)             = reH;
    *(ushort4*)(bh + (size_t)row*KDIM + 256 + 4*lane)       = urH;
    *(ushort4*)(bh + (size_t)(row+256)*KDIM + 4*lane)       = llH;
    *(ushort4*)(bh + (size_t)(row+256)*KDIM + 256 + 4*lane) = reH;
    *(ushort4*)(bl + (size_t)row*KDIM + 4*lane)             = reL;
    *(ushort4*)(bl + (size_t)row*KDIM + 256 + 4*lane)       = urL;
    *(ushort4*)(bl + (size_t)(row+256)*KDIM + 4*lane)       = llL;
    *(ushort4*)(bl + (size_t)(row+256)*KDIM + 256 + 4*lane) = reL;
}

// One MZI layer applied to TWO row states (a*, b*) sharing one coefficient set.
// cc[0..3] = (c0a,c0b,c1a,c1b). sp = physical layer index (parity selects path).
static __device__ __forceinline__ void layer_compute2(
    const float4 cc[4], int lane, int sp,
    float ar[4], float ai[4], float br[4], float bi[4])
{
    const float4 c0a = cc[0], c0b = cc[1], c1a = cc[2], c1b = cc[3];
    if ((sp & 1) == 0) {
        apply2(ar[0], ai[0], ar[1], ai[1], c0a, c0b);
        apply2(ar[2], ai[2], ar[3], ai[3], c1a, c1b);
        apply2(br[0], bi[0], br[1], bi[1], c0a, c0b);
        apply2(br[2], bi[2], br[3], bi[3], c1a, c1b);
    } else {
        float tAr = __shfl_down(ar[0], 1, 64);
        float tAi = __shfl_down(ai[0], 1, 64);
        float tBr = __shfl_down(br[0], 1, 64);
        float tBi = __shfl_down(bi[0], 1, 64);
        apply2(ar[1], ai[1], ar[2], ai[2], c0a, c0b);
        apply2(br[1], bi[1], br[2], bi[2], c0a, c0b);
        // row A boundary pair (4l+3, next lane's 4l+0)
        float x3r = ar[3], x3i = ai[3];
        float y3r = c1a.x*x3r - c1a.y*x3i + c1a.z*tAr - c1a.w*tAi;
        float y3i = c1a.x*x3i + c1a.y*x3r + c1a.z*tAi + c1a.w*tAr;
        float ynr = c1b.x*x3r - c1b.y*x3i + c1b.z*tAr - c1b.w*tAi;
        float yni = c1b.x*x3i + c1b.y*x3r + c1b.z*tAi + c1b.w*tAr;
        // row B boundary pair
        float w3r = br[3], w3i = bi[3];
        float z3r = c1a.x*w3r - c1a.y*w3i + c1a.z*tBr - c1a.w*tBi;
        float z3i = c1a.x*w3i + c1a.y*w3r + c1a.z*tBi + c1a.w*tBr;
        float znr = c1b.x*w3r - c1b.y*w3i + c1b.z*tBr - c1b.w*tBi;
        float zni = c1b.x*w3i + c1b.y*w3r + c1b.z*tBi + c1b.w*tBr;
        float rAr = __shfl_up(ynr, 1, 64);
        float rAi = __shfl_up(yni, 1, 64);
        float rBr = __shfl_up(znr, 1, 64);
        float rBi = __shfl_up(zni, 1, 64);
        if (lane != 63) { ar[3] = y3r; ai[3] = y3i; br[3] = z3r; bi[3] = z3i; }
        if (lane != 0)  { ar[0] = rAr; ai[0] = rAi; br[0] = rBr; bi[0] = rBi; }
    }
}

// 12 groups (it,chunk). chunk even: forward (S=Q^T); odd: reverse-transposed (S=Q);
// chunk 3 starts with gamma (S3=G*Q3). Chunks 1,2 stored CONJUGATE-embedded.
// 128 threads/block, 2 waves x 2 rows; LDS-staged coefficients, 4 layers/stage,
// 3-buffer rotation, counted vmcnt, 1 barrier per 4 layers. (~35us; final —
// serial-chain bound: throughput theories falsified rounds 2/7, occupancy
// invariant rounds 4/7, 8-way chain-split net-negative round 11.)
__global__ void propagate_kernel(const float* __restrict__ coef,
                                 const float* __restrict__ coefT,
                                 const float* __restrict__ gexp,
                                 unsigned short* __restrict__ chunkH,
                                 unsigned short* __restrict__ chunkL)
{
    __shared__ __align__(16) char smem[3 * 16384];   // 3 stages x 4 rows x 4KB

    const int tid  = threadIdx.x;              // 0..127
    const int lane = tid & 63;
    const int wv   = tid >> 6;                 // 0..1
    const int grp  = blockIdx.x >> 6;          // 0..11
    const int it   = grp >> 2, c = grp & 3;
    const int r0   = (blockIdx.x & 63) * 4 + wv * 2;   // this wave's rows
    const int r1   = r0 + 1;
    const bool rev = (c & 1);
    const bool cj  = (c == 1) || (c == 2);     // conjugate-embedded storage

    float ar[4], ai[4], br[4], bi[4];
    float gc0 = 1.0f, gs0 = 0.0f, gc1 = 1.0f, gs1 = 0.0f;
    if (c == 3) {
        gc0 = gexp[(it*NWG + r0)*2]; gs0 = gexp[(it*NWG + r0)*2 + 1];
        gc1 = gexp[(it*NWG + r1)*2]; gs1 = gexp[(it*NWG + r1)*2 + 1];
    }
#pragma unroll
    for (int e = 0; e < 4; ++e) {
        bool on0 = (4*lane + e) == r0;
        bool on1 = (4*lane + e) == r1;
        ar[e] = on0 ? gc0 : 0.0f;  ai[e] = on0 ? gs0 : 0.0f;
        br[e] = on1 ? gc1 : 0.0f;  bi[e] = on1 ? gs1 : 0.0f;
    }

    const char* cbb = (const char*)(rev ? coefT : coef)
                    + (size_t)(it*NWG + c*64) * (NPAIR * 32);   // 4096 B per layer row
    const int slot16 = (tid ^ ((tid >> 3) & 3)) * 16;

    auto stage = [&](int m) {
        char* dst = smem + (m % 3) * 16384;
#pragma unroll
        for (int q = 0; q < 4; ++q) {
            int s = 4*m + q;
            int r = rev ? 63 - s : s;
            const char* srow = cbb + (size_t)r * 4096;
            async16(srow + slot16,        dst + q*4096 + tid*16);
            async16(srow + slot16 + 2048, dst + q*4096 + tid*16 + 2048);
        }
    };

    stage(0); stage(1);                        // 16 loads in flight per thread

    const int sw = (lane >> 1) & 3;
    for (int m = 0; m < 16; ++m) {
        if (m < 15) asm volatile("s_waitcnt vmcnt(8)" ::: "memory");
        else        asm volatile("s_waitcnt vmcnt(0)" ::: "memory");
        __builtin_amdgcn_s_barrier();
        asm volatile("" ::: "memory");
        if (m < 14) stage(m + 2);
        const char* B = smem + (m % 3) * 16384;

        float4 cc[4][4];
#pragma unroll
        for (int q = 0; q < 4; ++q) {
            const char* Bq = B + q*4096;
            cc[q][0] = *(const float4*)(Bq + 16*(4*lane + (0 ^ sw)));
            cc[q][1] = *(const float4*)(Bq + 16*(4*lane + (1 ^ sw)));
            cc[q][2] = *(const float4*)(Bq + 16*(4*lane + (2 ^ sw)));
            cc[q][3] = *(const float4*)(Bq + 16*(4*lane + (3 ^ sw)));
        }
#pragma unroll
        for (int q = 0; q < 4; ++q) {
            int s = 4*m + q;
            layer_compute2(cc[q], lane, rev ? 63 - s : s, ar, ai, br, bi);
        }
    }

    unsigned short* bh = chunkH + (size_t)grp * MSZ;
    unsigned short* bl = chunkL + (size_t)grp * MSZ;
    store_row(bh, bl, r0, lane, cj, ar, ai);
    store_row(bh, bl, r1, lane, cj, br, bi);
}

// C = Ah*Bh^T + Ah*Bl^T + Al*Bh^T  (512x512, 64x64 tiles).
// mode0: z=it*2+wh. wh0: Pa^T = S0*S1^T (stored CONJUGATED: it is the B-operand
//        of mode1). wh1: Pb = S3*S2^T (stored plain). Outputs hi/lo split.
// mode1: z=it: E(M) = Pb * (Pa^T)^T -> bmat (single bf16)
// K-loop: 3-stage LDS pipeline, counted vmcnt(4), ONE barrier per K-step.
__global__ __launch_bounds__(256, 2) void compose_kernel(
    const unsigned short* __restrict__ srcH, const unsigned short* __restrict__ srcL,
    unsigned short* __restrict__ outH, unsigned short* __restrict__ outL,
    unsigned short* __restrict__ bmat, int mode)
{
    __shared__ unsigned short sAh[3][2048], sAl[3][2048], sBh[3][2048], sBl[3][2048];
    const int z = blockIdx.z;
    const unsigned short *Ah, *Al, *Bh, *Bl;
    if (mode == 0) {
        int it = z >> 1, wh = z & 1;
        int ai = it*4 + (wh ? 3 : 0), bi = it*4 + (wh ? 2 : 1);
        Ah = srcH + (size_t)ai*MSZ; Al = srcL + (size_t)ai*MSZ;
        Bh = srcH + (size_t)bi*MSZ; Bl = srcL + (size_t)bi*MSZ;
    } else {
        Ah = srcH + (size_t)(2*z+1)*MSZ; Al = srcL + (size_t)(2*z+1)*MSZ;
        Bh = srcH + (size_t)(2*z)*MSZ;   Bl = srcL + (size_t)(2*z)*MSZ;
    }
    const int tid = threadIdx.x, lane = tid & 63, wv = tid >> 6;
    const int quad = lane >> 4, l16 = lane & 15;
    const int m0 = blockIdx.x * 64, n0 = blockIdx.y * 64;
    const unsigned short* src = (wv==0)?Ah:(wv==1)?Al:(wv==2)?Bh:Bl;
    unsigned short (*dstb)[2048] = (wv==0)?sAh:(wv==1)?sAl:(wv==2)?sBh:sBl;
    const int r0 = (wv < 2) ? m0 : n0;
    const int trowb = lane >> 2, tcol = (lane & 3) * 8;

    const unsigned short* sp[4];
#pragma unroll
    for (int i = 0; i < 4; ++i)
        sp[i] = src + (size_t)(r0 + i*16 + trowb)*KDIM + tcol;

    auto stage = [&](int s) {
        int kt = s * 32, bs = s % 3;
#pragma unroll
        for (int i = 0; i < 4; ++i)
            async16(sp[i] + kt, &dstb[bs][i*512 + lane*8]);
    };
    stage(0); stage(1);                        // 8 loads in flight per thread

    floatx4 acc[4] = {};
    for (int s = 0; s < 16; ++s) {
        if (s < 15) asm volatile("s_waitcnt vmcnt(4)" ::: "memory");
        else        asm volatile("s_waitcnt vmcnt(0)" ::: "memory");
        __builtin_amdgcn_s_barrier();
        asm volatile("" ::: "memory");
        if (s < 14) stage(s + 2);
        const int bs = s % 3;
        short8 ah = *(const short8*)&sAh[bs][(16*wv + l16)*32 + quad*8];
        short8 al = *(const short8*)&sAl[bs][(16*wv + l16)*32 + quad*8];
#pragma unroll
        for (int ni = 0; ni < 4; ++ni) {
            short8 bh = *(const short8*)&sBh[bs][(16*ni + l16)*32 + quad*8];
            short8 bl = *(const short8*)&sBl[bs][(16*ni + l16)*32 + quad*8];
            acc[ni] = __builtin_amdgcn_mfma_f32_16x16x32_bf16(ah, bh, acc[ni], 0,0,0);
            acc[ni] = __builtin_amdgcn_mfma_f32_16x16x32_bf16(ah, bl, acc[ni], 0,0,0);
            acc[ni] = __builtin_amdgcn_mfma_f32_16x16x32_bf16(al, bh, acc[ni], 0,0,0);
        }
    }
#pragma unroll
    for (int ni = 0; ni < 4; ++ni)
#pragma unroll
        for (int rg = 0; rg < 4; ++rg) {
            int r = m0 + 16*wv + quad*4 + rg;
            int cc = n0 + 16*ni + l16;
            float v = acc[ni][rg];
            if (mode == 0) {
                float vs = (((z & 1) == 0) && ((r >= 256) != (cc >= 256))) ? -v : v;
                unsigned short h, l; bsplit(vs, h, l);
                outH[(size_t)z*MSZ + (size_t)r*KDIM + cc] = h;
                outL[(size_t)z*MSZ + (size_t)r*KDIM + cc] = l;
            } else {
                bmat[(size_t)z*MSZ + (size_t)r*KDIM + cc] = f2bf(v);
            }
        }
}

// Fused tail: convert + gemm0(EO) + gemm1(EO) + gemm2(intensity) + row-norm.
// 256 blocks x 512 threads (8 waves); block b owns rows [32b, 32b+32).
// x staged fp32->bf16 into XOR-swizzled LDS A-buffer (32 rows x 512 cols);
// Bmat streamed as [512 rows][32 kcols] 32KB tiles, 3-stage rotation, counted
// vmcnt(4), 1 barrier/K-step; continuous 48-step loop (3 gemms x 16 steps),
// B ptr = Bmat + (t/16)*MSZ. At t=16/32: EO rewrites the A-buffer in place
// (barrier-protected). Epilogue: cross-wave row-norm in LDS, 10-col output.
// Eliminates xbuf0/xbuf1/Ibuf (48 MB HBM) and 3 dispatch boundaries.
// Wave w owns logical cols [32w,32w+32): re B-rows n, im B-rows n+256.
__global__ __launch_bounds__(512, 1) void fused_tail_kernel(
    const unsigned short* __restrict__ Bmat,
    const float* __restrict__ xre, const float* __restrict__ xim,
    float* __restrict__ out)
{
    __shared__ __align__(16) char lds[131072];   // 96KB B (3 stages) + 32KB sX
    const int tid = threadIdx.x, lane = tid & 63, wv = tid >> 6;
    const int quad = lane >> 4, l16 = lane & 15;
    const int rbase = blockIdx.x * 32;
    const int nb = 32 * wv;

    // sX: row-major [32][512] bf16 at lds+98304, byte ^= ((row&7)<<4) swizzle
    auto sx = [&](int row, int colByte) -> char* {
        return lds + 98304 + row*1024 + (colByte ^ ((row & 7) << 4));
    };

    // ---- stage x (fp32 -> bf16) into sX
    {
        float4 v0[4], v1[4]; int xr_[4], xc_[4];
#pragma unroll
        for (int c = 0; c < 4; ++c) {
            int k = tid + c*512;
            int row = k >> 6, rem = k & 63, half = rem >> 5, j8 = (rem & 31) << 3;
            const float* s = (half ? xim : xre) + ((size_t)(rbase + row))*256 + j8;
            v0[c] = *(const float4*)s; v1[c] = *(const float4*)(s + 4);
            xr_[c] = row; xc_[c] = (half*256 + j8)*2;
        }
        asm volatile("s_waitcnt vmcnt(0)" ::: "memory");
#pragma unroll
        for (int c = 0; c < 4; ++c) {
            ushort8v u;
            u[0]=f2bf(v0[c].x); u[1]=f2bf(v0[c].y); u[2]=f2bf(v0[c].z); u[3]=f2bf(v0[c].w);
            u[4]=f2bf(v1[c].x); u[5]=f2bf(v1[c].y); u[6]=f2bf(v1[c].z); u[7]=f2bf(v1[c].w);
            *(ushort8v*)sx(xr_[c], xc_[c]) = u;
        }
    }

    auto stageB = [&](int t) {
        const unsigned short* src = Bmat + ((size_t)(t >> 4))*MSZ + (size_t)(t & 15)*32;
        char* dst = lds + (t % 3)*32768;
#pragma unroll
        for (int c = 0; c < 4; ++c) {
            int slot = tid + c*512, r = slot >> 2, q = slot & 3;
            async16(src + (size_t)r*KDIM + q*8, dst + slot*16);
        }
    };
    stageB(0); stageB(1);                      // 8 loads in flight per thread
    asm volatile("s_waitcnt lgkmcnt(0)" ::: "memory");

    floatx4 accr[2][2] = {}, acci[2][2] = {};

    for (int t = 0; t < 48; ++t) {
        if (t < 46) asm volatile("s_waitcnt vmcnt(4)" ::: "memory");
        else        asm volatile("s_waitcnt vmcnt(0)" ::: "memory");
        __builtin_amdgcn_s_barrier();          // stage t visible; readers of t-1 done
        asm volatile("" ::: "memory");
        if (t < 46) stageB(t + 2);             // buf (t+2)%3 last read at t-1

        if (t == 16 || t == 32) {
            // EO boundary: all reads of sX done (barrier above); rewrite in place
#pragma unroll
            for (int f = 0; f < 2; ++f)
#pragma unroll
            for (int nl = 0; nl < 2; ++nl)
#pragma unroll
            for (int rg = 0; rg < 4; ++rg) {
                float yr = accr[f][nl][rg], yi = acci[f][nl][rg];
                float I = yr*yr + yi*yi;
                float ph = 0.078539816339744831f * I + 1.5707963267948966f;
                float sp, cp; __sincosf(ph, &sp, &cp);
                float fm = 0.94868329805051381f * cp;
                int row = 16*f + quad*4 + rg;
                int col = nb + 16*nl + l16;
                *(unsigned short*)sx(row, col*2)       = f2bf(fm*(cp*yr + sp*yi));
                *(unsigned short*)sx(row, col*2 + 512) = f2bf(fm*(cp*yi - sp*yr));
            }
            asm volatile("s_waitcnt lgkmcnt(0)" ::: "memory");
            __builtin_amdgcn_s_barrier();
            asm volatile("" ::: "memory");
#pragma unroll
            for (int f = 0; f < 2; ++f)
#pragma unroll
            for (int nl = 0; nl < 2; ++nl) {
                accr[f][nl] = (floatx4){0.f,0.f,0.f,0.f};
                acci[f][nl] = (floatx4){0.f,0.f,0.f,0.f};
            }
        }

        const int kB = (t & 15) * 64;          // col-byte base in sX
        const char* Bb = lds + (t % 3)*32768;
        short8 a0 = *(const short8*)sx(l16,      kB + quad*16);
        short8 a1 = *(const short8*)sx(16 + l16, kB + quad*16);
        short8 br0 = *(const short8*)(Bb + (nb + l16)*64 + quad*16);
        short8 br1 = *(const short8*)(Bb + (nb + 16 + l16)*64 + quad*16);
        short8 bi0 = *(const short8*)(Bb + (256 + nb + l16)*64 + quad*16);
        short8 bi1 = *(const short8*)(Bb + (256 + nb + 16 + l16)*64 + quad*16);
        accr[0][0] = __builtin_amdgcn_mfma_f32_16x16x32_bf16(a0, br0, accr[0][0], 0,0,0);
        accr[0][1] = __builtin_amdgcn_mfma_f32_16x16x32_bf16(a0, br1, accr[0][1], 0,0,0);
        accr[1][0] = __builtin_amdgcn_mfma_f32_16x16x32_bf16(a1, br0, accr[1][0], 0,0,0);
        accr[1][1] = __builtin_amdgcn_mfma_f32_16x16x32_bf16(a1, br1, accr[1][1], 0,0,0);
        acci[0][0] = __builtin_amdgcn_mfma_f32_16x16x32_bf16(a0, bi0, acci[0][0], 0,0,0);
        acci[0][1] = __builtin_amdgcn_mfma_f32_16x16x32_bf16(a0, bi1, acci[0][1], 0,0,0);
        acci[1][0] = __builtin_amdgcn_mfma_f32_16x16x32_bf16(a1, bi0, acci[1][0], 0,0,0);
        acci[1][1] = __builtin_amdgcn_mfma_f32_16x16x32_bf16(a1, bi1, acci[1][1], 0,0,0);
    }

    // ---- epilogue: intensity + cross-wave row norm + 10-col output ----
    float I[2][2][4];
    float p[2][4];
#pragma unroll
    for (int f = 0; f < 2; ++f)
#pragma unroll
    for (int rg = 0; rg < 4; ++rg) {
        float s = 0.0f;
#pragma unroll
        for (int nl = 0; nl < 2; ++nl) {
            float yr = accr[f][nl][rg], yi = acci[f][nl][rg];
            float Iv = yr*yr + yi*yi;
            I[f][nl][rg] = Iv;
            s += Iv*Iv;
        }
        p[f][rg] = s;
    }
#pragma unroll
    for (int d = 1; d < 16; d <<= 1) {
#pragma unroll
        for (int f = 0; f < 2; ++f)
#pragma unroll
        for (int rg = 0; rg < 4; ++rg)
            p[f][rg] += __shfl_xor(p[f][rg], d, 64);   // reduce over l16 (in-quad)
    }
    float* scr = (float*)lds;                  // [8 waves][32 rows]
    if (l16 == 0) {
#pragma unroll
        for (int f = 0; f < 2; ++f)
#pragma unroll
        for (int rg = 0; rg < 4; ++rg)
            scr[wv*32 + 16*f + quad*4 + rg] = p[f][rg];
    }
    asm volatile("s_waitcnt lgkmcnt(0)" ::: "memory");
    __builtin_amdgcn_s_barrier();
    asm volatile("" ::: "memory");
    float* invb = (float*)(lds + 2048);        // [32 rows]
    if (tid < 32) {
        float s = 0.0f;
#pragma unroll
        for (int w = 0; w < 8; ++w) s += scr[w*32 + tid];
        invb[tid] = 1.0f / fmaxf(sqrtf(s), 1e-12f);
    }
    asm volatile("s_waitcnt lgkmcnt(0)" ::: "memory");
    __builtin_amdgcn_s_barrier();
    asm volatile("" ::: "memory");
    if (wv == 0 && l16 < 10) {                 // cols 0..9 live in wave 0, nl=0
#pragma unroll
        for (int f = 0; f < 2; ++f)
#pragma unroll
        for (int rg = 0; rg < 4; ++rg) {
            int row = 16*f + quad*4 + rg;
            out[((size_t)(rbase + row))*10 + l16] = I[f][0][rg] * invb[row];
        }
    }
}

extern "C" void kernel_launch(void* const* d_in, const int* in_sizes, int n_in,
                              void* d_out, int out_size, void* d_ws, size_t ws_size,
                              hipStream_t stream)
{
    const float* x_real = (const float*)d_in[0];
    const float* x_imag = (const float*)d_in[1];
    const float* theta  = (const float*)d_in[2];
    const float* phi    = (const float*)d_in[3];
    const float* gamma  = (const float*)d_in[4];

    char* ws = (char*)d_ws;
    float* coef  = (float*)(ws + 0);              // 3 MB   [precompute->propagate]
    float* coefT = (float*)(ws + 3145728);        // 3 MB
    float* gexp  = (float*)(ws + 6291456);        // 6 KB
    unsigned short* chunkH = (unsigned short*)(ws + 6297600);   // 6 MB
    unsigned short* chunkL = (unsigned short*)(ws + 12589056);  // 6 MB
    unsigned short* PH   = (unsigned short*)(ws + 0);           // 3 MB (alias coef)
    unsigned short* PL   = (unsigned short*)(ws + 3145728);     // 3 MB (alias coefT)
    unsigned short* Bmat = (unsigned short*)(ws + 23074816);    // 1.5 MB

    precompute_kernel<<<(NITER*NWG*NPAIR + 255)/256, 256, 0, stream>>>(
        theta, phi, gamma, coef, coefT, gexp);

    // 768 blocks x 128 threads: 2 waves/block, 2 rows/wave (3072 rows total)
    propagate_kernel<<<768, 128, 0, stream>>>(coef, coefT, gexp, chunkH, chunkL);

    compose_kernel<<<dim3(8,8,6), 256, 0, stream>>>(chunkH, chunkL, PH, PL, Bmat, 0);
    compose_kernel<<<dim3(8,8,3), 256, 0, stream>>>(PH, PL, PH, PL, Bmat, 1);

    fused_tail_kernel<<<256, 512, 0, stream>>>(Bmat, x_real, x_imag, (float*)d_out);
}